// Round 2
// baseline (36.468 us; speedup 1.0000x reference)
//
#include <hip/hip_runtime.h>
#include <math.h>

#define ALPHA 0.2f

constexpr int BB   = 4;
constexpr int NN_  = 4096;
constexpr int HN   = 2048;      // N/2
constexpr int FIN  = 128;
constexpr int FF   = 64;
constexpr int ROWS = BB * NN_;  // 16384

// ---- workspace layout (floats) ----
constexpr size_t WS_H  = 0;                          // ROWS*FF   (h matrix, 4 MB)
constexpr size_t WS_C  = (size_t)ROWS * FF;          // ROWS      (c = s1+s2 per row)
constexpr size_t WS_E  = WS_C + ROWS;                // ROWS      (e = even? s1 : s2)
constexpr size_t WS_A0 = WS_E + ROWS;                // BB*FF
constexpr size_t WS_A1 = WS_A0 + (size_t)BB * FF;    // BB*FF
constexpr size_t WS_U  = WS_A1 + (size_t)BB * FF;    // BB*FF
constexpr size_t WS_M  = WS_U + (size_t)BB * FF;     // 2*BB (M0,M1 per batch)
// total ~4.33 MB

// ================= K1: h = inp @ W, plus per-row dots c,e =================
// W held in 128 VGPRs per lane (lane = output feature f).
// Row data read through wave-uniform pointers -> scalar loads broadcast.
__global__ __launch_bounds__(256) void k1_gemm(const float* __restrict__ inp,
                                               const float* __restrict__ W,
                                               const float* __restrict__ a,
                                               float* __restrict__ ws) {
  const int lane = threadIdx.x & 63;
  const int wv = __builtin_amdgcn_readfirstlane((int)(threadIdx.x >> 6));
  const int rowbase = blockIdx.x * 32 + wv * 8;   // 8 rows per wave, 32 per block

  float Wreg[FIN];
  #pragma unroll
  for (int k = 0; k < FIN; ++k) Wreg[k] = W[k * FF + lane];

  const float a1 = a[lane];
  const float a2 = a[FF + lane];
  const float asum = a1 + a2;

  float* hout = ws + WS_H;
  float* cout = ws + WS_C;
  float* eout = ws + WS_E;

  // zero the atomic accumulators (A0,A1,u) once per launch
  if (blockIdx.x == 0) {
    for (int t = threadIdx.x; t < 3 * BB * FF; t += 256) ws[WS_A0 + t] = 0.f;
  }

  for (int p = 0; p < 4; ++p) {
    const int r0 = rowbase + 2 * p;               // r0 even, r0+1 odd
    const float* p0 = inp + (size_t)r0 * FIN;
    const float* p1 = p0 + FIN;
    float h0a = 0.f, h0b = 0.f, h1a = 0.f, h1b = 0.f;
    #pragma unroll
    for (int k = 0; k < FIN; k += 2) {
      h0a = fmaf(p0[k],     Wreg[k],     h0a);
      h0b = fmaf(p0[k + 1], Wreg[k + 1], h0b);
      h1a = fmaf(p1[k],     Wreg[k],     h1a);
      h1b = fmaf(p1[k + 1], Wreg[k + 1], h1b);
    }
    const float h0 = h0a + h0b;
    const float h1 = h1a + h1b;
    hout[(size_t)r0 * FF + lane] = h0;
    hout[(size_t)(r0 + 1) * FF + lane] = h1;

    // per-row dot products across the 64 features (butterfly reduce)
    float c0 = h0 * asum, e0 = h0 * a1;   // even row -> need s1
    float c1 = h1 * asum, e1 = h1 * a2;   // odd row  -> need s2
    #pragma unroll
    for (int s = 32; s >= 1; s >>= 1) {
      c0 += __shfl_xor(c0, s, 64);
      e0 += __shfl_xor(e0, s, 64);
      c1 += __shfl_xor(c1, s, 64);
      e1 += __shfl_xor(e1, s, 64);
    }
    if (lane == 0) {
      cout[r0] = c0;     eout[r0] = e0;
      cout[r0 + 1] = c1; eout[r0 + 1] = e1;
    }
  }
}

// ================= K3: stats + weighted column sums =================
// Each block recomputes (M0,M1,P0,P1) from c (16 KB), computes per-column
// weights q,w for its 128-row segment, accumulates A0/A1/u via atomics.
constexpr int NSEG = 32;   // segments per batch
constexpr int SEGR = 128;  // rows per segment

__global__ __launch_bounds__(256) void k3_colsum(float* __restrict__ ws) {
  const int b   = blockIdx.x / NSEG;
  const int seg = blockIdx.x % NSEG;
  const int tid = threadIdx.x;
  const float* c = ws + WS_C + (size_t)b * NN_;
  const float* e = ws + WS_E + (size_t)b * NN_;
  const float* h = ws + WS_H + (size_t)b * NN_ * FF;

  __shared__ float lr_s[NN_];          // 16 KB
  __shared__ float red[256];
  __shared__ float qbuf[SEGR];
  __shared__ float wbuf[SEGR];
  __shared__ float accbuf[4][2][64];

  // parity-preserving max over lr(c): even stride keeps tid parity == k parity
  float mymax = -INFINITY;
  for (int k = tid; k < NN_; k += 256) {
    float x = c[k];
    x = x > 0.f ? x : ALPHA * x;
    lr_s[k] = x;
    mymax = fmaxf(mymax, x);
  }
  red[tid] = mymax;
  __syncthreads();
  #pragma unroll
  for (int s = 128; s >= 2; s >>= 1) {
    if (tid < s) red[tid] = fmaxf(red[tid], red[tid + s]);
    __syncthreads();
  }
  const float M0 = red[0];
  const float M1 = red[1];
  __syncthreads();

  const float Mp = (tid & 1) ? M1 : M0;
  float mysum = 0.f;
  for (int k = tid; k < NN_; k += 256) mysum += __expf(lr_s[k] - Mp);
  red[tid] = mysum;
  __syncthreads();
  #pragma unroll
  for (int s = 128; s >= 2; s >>= 1) {
    if (tid < s) red[tid] += red[tid + s];
    __syncthreads();
  }
  const float P0 = red[0];
  const float P1 = red[1];

  // per-column weights for this segment
  if (tid < SEGR) {
    const int j  = seg * SEGR + tid;       // column index in [0,N)
    const int jp = j & (HN - 1);           // d is periodic with period N/2
    float d = e[2 * jp] + e[2 * jp + 1];
    float v = d > 0.f ? d : ALPHA * d;
    float Mt = (j < HN) ? M0 : M1;
    float Pt = (j < HN) ? P0 : P1;
    float m  = fmaxf(Mt, v);
    float eM = __expf(Mt - m);
    float ev = __expf(v - m);
    float Z  = eM * Pt + (float)HN * ev;
    qbuf[tid] = eM / Z;
    wbuf[tid] = ev / Z;
  }
  if (seg == 0 && tid == 0) {
    ws[WS_M + 2 * b]     = M0;
    ws[WS_M + 2 * b + 1] = M1;
  }
  __syncthreads();

  // weighted sums over this segment's rows of h
  const int wv = tid >> 6;
  const int lane = tid & 63;
  float accA = 0.f, accU = 0.f;
  const int lbase = wv * (SEGR / 4);
  #pragma unroll 4
  for (int r = 0; r < SEGR / 4; ++r) {
    const int lj = lbase + r;
    const int j  = seg * SEGR + lj;
    float hv = h[(size_t)j * FF + lane];
    accA = fmaf(qbuf[lj], hv, accA);
    accU = fmaf(wbuf[lj], hv, accU);
  }
  accbuf[wv][0][lane] = accA;
  accbuf[wv][1][lane] = accU;
  __syncthreads();
  if (tid < 64) {
    float sA = accbuf[0][0][tid] + accbuf[1][0][tid] + accbuf[2][0][tid] + accbuf[3][0][tid];
    float sU = accbuf[0][1][tid] + accbuf[1][1][tid] + accbuf[2][1][tid] + accbuf[3][1][tid];
    float* A = ws + ((seg < NSEG / 2) ? WS_A0 : WS_A1) + (size_t)b * FF;
    atomicAdd(&A[tid], sA);
    atomicAdd(ws + WS_U + (size_t)b * FF + tid, sU);
  }
}

// ================= K4: rank-2 reconstruction + elu =================
__global__ __launch_bounds__(256) void k4_out(const float* __restrict__ ws,
                                              float* __restrict__ out) {
  const int idx = blockIdx.x * 256 + threadIdx.x;  // float4 group, B*N*16 total
  const int b   = idx >> 16;                       // N*16 = 65536 groups/batch
  const int rem = idx & 65535;
  const int i   = rem >> 4;
  const int fg  = rem & 15;
  float4 v;
  if (i < HN) {
    const float* c = ws + WS_C + (size_t)b * NN_;
    const float M0 = ws[WS_M + 2 * b];
    const float M1 = ws[WS_M + 2 * b + 1];
    float c0 = c[2 * i], c1 = c[2 * i + 1];
    c0 = c0 > 0.f ? c0 : ALPHA * c0;
    c1 = c1 > 0.f ? c1 : ALPHA * c1;
    const float al = __expf(c0 - M0);
    const float be = __expf(c1 - M1);
    const float4 A0v = reinterpret_cast<const float4*>(ws + WS_A0 + (size_t)b * FF)[fg];
    const float4 A1v = reinterpret_cast<const float4*>(ws + WS_A1 + (size_t)b * FF)[fg];
    v.x = al * A0v.x + be * A1v.x;
    v.y = al * A0v.y + be * A1v.y;
    v.z = al * A0v.z + be * A1v.z;
    v.w = al * A0v.w + be * A1v.w;
  } else {
    v = reinterpret_cast<const float4*>(ws + WS_U + (size_t)b * FF)[fg];
  }
  v.x = v.x > 0.f ? v.x : expm1f(v.x);
  v.y = v.y > 0.f ? v.y : expm1f(v.y);
  v.z = v.z > 0.f ? v.z : expm1f(v.z);
  v.w = v.w > 0.f ? v.w : expm1f(v.w);
  reinterpret_cast<float4*>(out)[idx] = v;
}

extern "C" void kernel_launch(void* const* d_in, const int* in_sizes, int n_in,
                              void* d_out, int out_size, void* d_ws, size_t ws_size,
                              hipStream_t stream) {
  (void)in_sizes; (void)n_in; (void)out_size; (void)ws_size;
  const float* inp = (const float*)d_in[0];
  const float* W   = (const float*)d_in[1];
  const float* a   = (const float*)d_in[2];
  float* out = (float*)d_out;
  float* ws  = (float*)d_ws;

  hipLaunchKernelGGL(k1_gemm,   dim3(ROWS / 32),        dim3(256), 0, stream, inp, W, a, ws);
  hipLaunchKernelGGL(k3_colsum, dim3(BB * NSEG),        dim3(256), 0, stream, ws);
  hipLaunchKernelGGL(k4_out,    dim3(ROWS * FF / 1024), dim3(256), 0, stream, ws, out);
}

// Round 5
// 34.987 us; speedup vs baseline: 1.0423x; 1.0423x over previous
//
#include <hip/hip_runtime.h>
#include <math.h>

#define ALPHA 0.2f

constexpr int BB   = 4;
constexpr int NN_  = 4096;
constexpr int HN   = 2048;      // N/2
constexpr int FIN  = 128;
constexpr int FF   = 64;
constexpr int ROWS = BB * NN_;  // 16384

// ---- workspace layout (float offsets; ws is 256 MiB, we use ~4.5 MB) ----
constexpr size_t WS_H  = 0;                          // ROWS*FF  h matrix (4 MB)
constexpr size_t WS_C  = (size_t)ROWS * FF;          // ROWS     c = s1+s2 per row
constexpr size_t WS_E  = WS_C + ROWS;                // ROWS     e = even? s1 : s2
constexpr size_t WS_A0 = WS_E + ROWS;                // BB*FF
constexpr size_t WS_A1 = WS_A0 + (size_t)BB * FF;    // BB*FF
constexpr size_t WS_U  = WS_A1 + (size_t)BB * FF;    // BB*FF
constexpr size_t WS_M  = WS_U + (size_t)BB * FF;     // 2*BB  (M0,M1 per batch)
constexpr size_t WS_WQ = WS_M + 2 * BB;              // BB*HN*4  weight table (float4/jp)

// ================= K1: h = inp @ W + per-row dots c,e =================
// Rows staged in LDS (coalesced float4), W in 128 VGPRs (lane = out feature).
// Row values read as uniform-address ds_read_b128 broadcasts.
__global__ __launch_bounds__(256) void k1_gemm(const float* __restrict__ inp,
                                               const float* __restrict__ W,
                                               const float* __restrict__ a,
                                               float* __restrict__ ws) {
  const int tid  = threadIdx.x;
  const int lane = tid & 63;
  const int wv   = __builtin_amdgcn_readfirstlane(tid >> 6);
  __shared__ float rows_s[32 * FIN];   // 16 KB

  float Wreg[FIN];
  #pragma unroll
  for (int k = 0; k < FIN; ++k) Wreg[k] = W[k * FF + lane];
  const float a1 = a[lane];
  const float a2 = a[FF + lane];
  const float asum = a1 + a2;

  const int rowbase = blockIdx.x * 32;
  const float4* src = reinterpret_cast<const float4*>(inp + (size_t)rowbase * FIN);
  float4* dst = reinterpret_cast<float4*>(rows_s);
  #pragma unroll
  for (int i = 0; i < 4; ++i) dst[tid + i * 256] = src[tid + i * 256];
  __syncthreads();

  float* hout = ws + WS_H;
  float* cout = ws + WS_C;
  float* eout = ws + WS_E;

  #pragma unroll
  for (int p = 0; p < 4; ++p) {
    const int lr0 = wv * 8 + 2 * p;                 // local even row
    const float* rp0 = rows_s + lr0 * FIN;
    const float* rp1 = rp0 + FIN;
    float h0 = 0.f, h0b = 0.f, h1 = 0.f, h1b = 0.f;
    #pragma unroll
    for (int k = 0; k < FIN; k += 4) {
      const float4 x0 = *reinterpret_cast<const float4*>(rp0 + k);
      const float4 x1 = *reinterpret_cast<const float4*>(rp1 + k);
      h0  = fmaf(x0.x, Wreg[k],     h0);
      h0b = fmaf(x0.y, Wreg[k + 1], h0b);
      h0  = fmaf(x0.z, Wreg[k + 2], h0);
      h0b = fmaf(x0.w, Wreg[k + 3], h0b);
      h1  = fmaf(x1.x, Wreg[k],     h1);
      h1b = fmaf(x1.y, Wreg[k + 1], h1b);
      h1  = fmaf(x1.z, Wreg[k + 2], h1);
      h1b = fmaf(x1.w, Wreg[k + 3], h1b);
    }
    const float H0 = h0 + h0b;
    const float H1 = h1 + h1b;
    const int r0 = rowbase + lr0;
    hout[(size_t)r0 * FF + lane] = H0;
    hout[(size_t)(r0 + 1) * FF + lane] = H1;

    float c0 = H0 * asum, e0 = H0 * a1;   // even row -> s1
    float c1 = H1 * asum, e1 = H1 * a2;   // odd row  -> s2
    #pragma unroll
    for (int s = 32; s >= 1; s >>= 1) {
      c0 += __shfl_xor(c0, s, 64);
      e0 += __shfl_xor(e0, s, 64);
      c1 += __shfl_xor(c1, s, 64);
      e1 += __shfl_xor(e1, s, 64);
    }
    if (lane == 0) {
      cout[r0] = c0;     eout[r0] = e0;
      cout[r0 + 1] = c1; eout[r0 + 1] = e1;
    }
  }
}

// ================= K2: per-batch stats + weight table =================
// grid = BB blocks x 1024 threads. Computes M0,M1,P0,P1 once, emits
// (q0,w0,q1,w1) per jp in [0,HN), zeroes the atomic accumulators.
__global__ __launch_bounds__(1024) void k2_stats(float* __restrict__ ws) {
  const int b    = blockIdx.x;
  const int tid  = threadIdx.x;
  const int lane = tid & 63;
  const int w    = tid >> 6;                 // 16 waves
  const float* c = ws + WS_C + (size_t)b * NN_;
  const float* e = ws + WS_E + (size_t)b * NN_;
  __shared__ float redm[16][2];
  __shared__ float bc[4];

  const float4 cv = reinterpret_cast<const float4*>(c)[tid];
  const float l0 = cv.x > 0.f ? cv.x : ALPHA * cv.x;
  const float l1 = cv.y > 0.f ? cv.y : ALPHA * cv.y;
  const float l2 = cv.z > 0.f ? cv.z : ALPHA * cv.z;
  const float l3 = cv.w > 0.f ? cv.w : ALPHA * cv.w;
  float me = fmaxf(l0, l2), mo = fmaxf(l1, l3);
  #pragma unroll
  for (int s = 32; s >= 1; s >>= 1) {
    me = fmaxf(me, __shfl_xor(me, s, 64));
    mo = fmaxf(mo, __shfl_xor(mo, s, 64));
  }
  if (lane == 0) { redm[w][0] = me; redm[w][1] = mo; }
  __syncthreads();
  if (tid == 0) {
    float M0 = -INFINITY, M1 = -INFINITY;
    for (int i = 0; i < 16; ++i) {
      M0 = fmaxf(M0, redm[i][0]);
      M1 = fmaxf(M1, redm[i][1]);
    }
    bc[0] = M0; bc[1] = M1;
  }
  __syncthreads();
  const float M0 = bc[0], M1 = bc[1];
  float se = __expf(l0 - M0) + __expf(l2 - M0);
  float so = __expf(l1 - M1) + __expf(l3 - M1);
  #pragma unroll
  for (int s = 32; s >= 1; s >>= 1) {
    se += __shfl_xor(se, s, 64);
    so += __shfl_xor(so, s, 64);
  }
  __syncthreads();
  if (lane == 0) { redm[w][0] = se; redm[w][1] = so; }
  __syncthreads();
  if (tid == 0) {
    float P0 = 0.f, P1 = 0.f;
    for (int i = 0; i < 16; ++i) { P0 += redm[i][0]; P1 += redm[i][1]; }
    bc[2] = P0; bc[3] = P1;
    ws[WS_M + 2 * b]     = M0;
    ws[WS_M + 2 * b + 1] = M1;
  }
  __syncthreads();
  const float P0 = bc[2], P1 = bc[3];

  float4* wq = reinterpret_cast<float4*>(ws + WS_WQ) + (size_t)b * HN;
  #pragma unroll
  for (int i = 0; i < 2; ++i) {
    const int jp = tid + i * 1024;
    const float2 ev = reinterpret_cast<const float2*>(e)[jp];
    const float d = ev.x + ev.y;
    const float v = d > 0.f ? d : ALPHA * d;
    const float m0 = fmaxf(M0, v), m1 = fmaxf(M1, v);
    const float eM0 = __expf(M0 - m0), ev0 = __expf(v - m0);
    const float eM1 = __expf(M1 - m1), ev1 = __expf(v - m1);
    const float Z0 = eM0 * P0 + (float)HN * ev0;
    const float Z1 = eM1 * P1 + (float)HN * ev1;
    wq[jp] = make_float4(eM0 / Z0, ev0 / Z0, eM1 / Z1, ev1 / Z1);
  }
  if (tid < FF) {
    ws[WS_A0 + (size_t)b * FF + tid] = 0.f;
    ws[WS_A1 + (size_t)b * FF + tid] = 0.f;
    ws[WS_U  + (size_t)b * FF + tid] = 0.f;
  }
}

// ================= K3: weighted column sums =================
constexpr int NSEG = 32;   // segments per batch
constexpr int SEGR = 128;  // rows per segment

__global__ __launch_bounds__(256) void k3_colsum(float* __restrict__ ws) {
  const int b    = blockIdx.x >> 5;
  const int seg  = blockIdx.x & 31;
  const int tid  = threadIdx.x;
  const int lane = tid & 63;
  const int wv   = __builtin_amdgcn_readfirstlane(tid >> 6);
  const float* h = ws + WS_H + (size_t)b * NN_ * FF;
  const float4* wq = reinterpret_cast<const float4*>(ws + WS_WQ) + (size_t)b * HN;
  __shared__ float accbuf[4][2][64];

  const int j0 = seg * SEGR + wv * 32;
  float accA = 0.f, accU = 0.f;
  #pragma unroll 8
  for (int r = 0; r < 32; ++r) {
    const int j = j0 + r;
    const float hv = h[(size_t)j * FF + lane];
    const float4 q = wq[j & (HN - 1)];
    const float qa = (j < HN) ? q.x : q.z;
    const float qu = (j < HN) ? q.y : q.w;
    accA = fmaf(qa, hv, accA);
    accU = fmaf(qu, hv, accU);
  }
  accbuf[wv][0][lane] = accA;
  accbuf[wv][1][lane] = accU;
  __syncthreads();
  if (tid < 64) {
    const float sA = accbuf[0][0][tid] + accbuf[1][0][tid] + accbuf[2][0][tid] + accbuf[3][0][tid];
    const float sU = accbuf[0][1][tid] + accbuf[1][1][tid] + accbuf[2][1][tid] + accbuf[3][1][tid];
    float* A = ws + ((seg < NSEG / 2) ? WS_A0 : WS_A1) + (size_t)b * FF;
    atomicAdd(&A[tid], sA);
    atomicAdd(ws + WS_U + (size_t)b * FF + tid, sU);
  }
}

// ================= K4: rank-2 reconstruction + elu =================
__global__ __launch_bounds__(256) void k4_out(const float* __restrict__ ws,
                                              float* __restrict__ out) {
  const int idx = blockIdx.x * 256 + threadIdx.x;  // float4 group, B*N*16 total
  const int b   = idx >> 16;
  const int rem = idx & 65535;
  const int i   = rem >> 4;
  const int fg  = rem & 15;
  float4 v;
  if (i < HN) {
    const float* c = ws + WS_C + (size_t)b * NN_;
    const float M0 = ws[WS_M + 2 * b];
    const float M1 = ws[WS_M + 2 * b + 1];
    float c0 = c[2 * i], c1 = c[2 * i + 1];
    c0 = c0 > 0.f ? c0 : ALPHA * c0;
    c1 = c1 > 0.f ? c1 : ALPHA * c1;
    const float al = __expf(c0 - M0);
    const float be = __expf(c1 - M1);
    const float4 A0v = reinterpret_cast<const float4*>(ws + WS_A0 + (size_t)b * FF)[fg];
    const float4 A1v = reinterpret_cast<const float4*>(ws + WS_A1 + (size_t)b * FF)[fg];
    v.x = al * A0v.x + be * A1v.x;
    v.y = al * A0v.y + be * A1v.y;
    v.z = al * A0v.z + be * A1v.z;
    v.w = al * A0v.w + be * A1v.w;
  } else {
    v = reinterpret_cast<const float4*>(ws + WS_U + (size_t)b * FF)[fg];
  }
  v.x = v.x > 0.f ? v.x : expm1f(v.x);
  v.y = v.y > 0.f ? v.y : expm1f(v.y);
  v.z = v.z > 0.f ? v.z : expm1f(v.z);
  v.w = v.w > 0.f ? v.w : expm1f(v.w);
  reinterpret_cast<float4*>(out)[idx] = v;
}

extern "C" void kernel_launch(void* const* d_in, const int* in_sizes, int n_in,
                              void* d_out, int out_size, void* d_ws, size_t ws_size,
                              hipStream_t stream) {
  (void)in_sizes; (void)n_in; (void)out_size; (void)ws_size;
  const float* inp = (const float*)d_in[0];
  const float* W   = (const float*)d_in[1];
  const float* a   = (const float*)d_in[2];
  float* out = (float*)d_out;
  float* ws  = (float*)d_ws;

  hipLaunchKernelGGL(k1_gemm,   dim3(ROWS / 32),        dim3(256),  0, stream, inp, W, a, ws);
  hipLaunchKernelGGL(k2_stats,  dim3(BB),               dim3(1024), 0, stream, ws);
  hipLaunchKernelGGL(k3_colsum, dim3(BB * NSEG),        dim3(256),  0, stream, ws);
  hipLaunchKernelGGL(k4_out,    dim3(ROWS * FF / 1024), dim3(256),  0, stream, ws, out);
}